// Round 13
// baseline (202.530 us; speedup 1.0000x reference)
//
#include <hip/hip_runtime.h>

// VectorQuantize: B=4, N=2048, DIM=256, HEADS=4, CODEBOOK=8192, HD=64
// Established: inputs fp32, output fp32 (quantize ++ indices-as-floats).
// R10: fp16 2-level split, 3 MFMA terms. R11: setprio+z-init: dist 128.
// R12: threadfence fusion DISASTER. R13: fence-free atomic fusion 137/176.
// R15: counted-wait barriers NEUTRAL. R16: prep planes + gl_lds: 131.5/176.0
//   (BEST). R17: barrier-free private tiles REGRESSED. R18: coop crash.
// R19/R22: R16 reproduced (130-131 / 176-177). R21: 32x32 shape CLOSED
//   (spill + inherent 4-way LDS conflict).
// R20 AUDIT FLAW: it tested 5 waves/SIMD -- NOT A VALID SLOT (m69: waves
//   quantize at VGPR 64/128/256). The valid 8-waves/SIMD @ <=64 VGPR cell
//   was never reachable with rt>=2 geometry (>=96 live regs).
// R23 (this round): true 8-wave probe. rt=1 (16 q/wave) -> live state
//   ~56-62 regs (A 16 + bv/bc 8 + b 16 + acc 8 + addr). SCODES=32 ->
//   LDS 16.6KB -> 8 blocks/CU. Grid 4096 = 4h x 128qg x 8part;
//   launch_bounds(256,8) targets the 64-reg slot = 32 waves/CU (2x TLP).
//   Same verified swizzle/election algebra, 64-query groups. Decisive
//   counters: VGPR(=64 no-spill?) / WRITE_SIZE(~17MB?) / dist.
//   Win -> ~90-110us dist. Spill or convoy -> cell closed validly,
//   R24 restores R19 and declares the structural floor.

#define HEADS    4
#define CODEBOOK 8192
#define HD       64
#define BQ       8192                  // queries per head = B*N
#define QOFF     (4 * 2048 * 256)      // quantize FLOAT elements in d_out
#define NPART    8
#define CPART    (CODEBOOK / NPART)    // 1024 codes per partition
#define SCODES   32                    // codes per stage
#define NSTAGE   (CPART / SCODES)      // 32 stages
#define QBLOCK   64                    // queries per block (4 waves x 16)
#define RSCALE   4096.0f               // residual scale (2^12)
#define RINV     (1.0f / 4096.0f)

typedef _Float16 f16x8 __attribute__((ext_vector_type(8)));
typedef float    f32x4 __attribute__((ext_vector_type(4)));

__device__ _Float16 g_e0[HEADS * CODEBOOK * HD];  // 4 MB: fp16 level-0 plane
__device__ _Float16 g_e1[HEADS * CODEBOOK * HD];  // 4 MB: fp16 level-1 plane
__device__ float    g_y2[HEADS * CODEBOOK];       // -0.5*||e||^2
__device__ unsigned long long g_best[HEADS * BQ]; // packed (sortable score, ~idx)
__device__ int                g_cnt[HEADS * 128]; // per-(h,qg) arrival counter

// split fp32 -> 2 fp16 levels: f ~= (float)h0 + (float)h1 / 4096, |err|<=2^-24|f|
__device__ inline void split2(float f, _Float16& h0, _Float16& h1) {
    h0 = (_Float16)f;
    float r = f - (float)h0;
    h1 = (_Float16)(r * RSCALE);
}

// order-preserving float->uint32 (finite values; scores are finite)
__device__ inline unsigned sortable(float v) {
    unsigned s = __float_as_uint(v);
    return s ^ ((s & 0x80000000u) ? 0xFFFFFFFFu : 0x80000000u);
}

__device__ inline void gl_lds16(const void* g, void* l) {
    __builtin_amdgcn_global_load_lds(
        (const __attribute__((address_space(1))) void*)g,
        (__attribute__((address_space(3))) void*)l, 16, 0, 0);
}

// ---------------- kernel 0: pre-split embed into global planes ------------
// 1024 blocks x 256 thr; 8 threads per code row (granule t&7), 32 rows/block.
__global__ __launch_bounds__(256) void prep_kernel(const float* __restrict__ embed) {
    const int t   = threadIdx.x;
    const int row = blockIdx.x * 32 + (t >> 3);    // h*CODEBOOK + c
    const int g   = t & 7;
    const float* p = embed + (size_t)row * HD + g * 8;
    float f[8];
    *reinterpret_cast<float4*>(&f[0]) = *reinterpret_cast<const float4*>(p);
    *reinterpret_cast<float4*>(&f[4]) = *reinterpret_cast<const float4*>(p + 4);
    f16x8 v0, v1;
    float ss = 0.f;
#pragma unroll
    for (int j = 0; j < 8; j++) {
        _Float16 h0, h1;
        split2(f[j], h0, h1);
        v0[j] = h0; v1[j] = h1;
        ss = fmaf(f[j], f[j], ss);
    }
    *reinterpret_cast<f16x8*>(&g_e0[(size_t)row * HD + g * 8]) = v0;
    *reinterpret_cast<f16x8*>(&g_e1[(size_t)row * HD + g * 8]) = v1;
#pragma unroll
    for (int off = 4; off >= 1; off >>= 1)
        ss += __shfl_xor(ss, off, 8);
    if (g == 0) g_y2[row] = -0.5f * ss;
}

// ---------------- kernel 1: fused scores + argmax + election merge --------
// grid = 4096 = head(4) x qgroup(128) x part(8); block = 256 (4 waves).
// Each wave owns 16 queries (1 pinned A row-tile); block scans one 1024-code
// partition in 32 stages of 32 codes. Staging = 8 global_load_lds (16B) per
// stage per block (2/wave: wave w covers plane w&1, rows (w>>1)*16..+15),
// source pre-swizzled so LDS layout == verified conflict-free tile:
// LDS slot g of row rr holds global granule g^(rr&7).
// MFMA 16x16x32_f16 layouts (HW-verified family):
//   A: lane -> A[m=lane&15][k=quad*8+j];  B: lane -> B[k=quad*8+j][n=lane&15]
//   C: lane -> col=lane&15, row=quad*4+reg
__global__ __launch_bounds__(256, 8) void dist_kernel(const float* __restrict__ x,
                                                      const float* __restrict__ embed,
                                                      float* __restrict__ out) {
    __shared__ __align__(16) _Float16 tile[2][2][SCODES * HD];   // 16384 B
    __shared__ int s_old;

    const int bid  = blockIdx.x;
    const int part = bid & 7;
    const int qg   = (bid >> 3) & 127;
    const int h    = bid >> 10;
    const int t    = threadIdx.x;
    const int wave = t >> 6;
    const int lane = t & 63;
    const int col  = lane & 15;
    const int quad = lane >> 4;

    const int qbase = qg * QBLOCK + wave * 16;    // this wave's 16 queries
    const int cbase = part * CPART;

    // staging geometry: wave covers plane (wave&1), rows (wave>>1)*16..+15.
    // lane l: row-in-chunk l>>3, LDS slot l&7 (HW lane-linear), source
    // granule (l&7)^(l>>3)  [row&7 == l>>3 since all bases are %8==0].
    const int p  = wave & 1;
    const int hh = wave >> 1;
    const _Float16* eb   = p ? g_e1 : g_e0;
    const _Float16* gsrc = eb
        + ((size_t)(h * CODEBOOK + cbase + hh * 16 + (lane >> 3))) * HD
        + ((lane & 7) ^ (lane >> 3)) * 8;
    auto stage_issue = [&](int st, int buf) {
        const _Float16* src = gsrc + (size_t)st * (SCODES * HD);
#pragma unroll
        for (int i = 0; i < 2; i++)
            gl_lds16(src + i * 8 * HD, &tile[buf][p][(hh * 16 + i * 8) * HD]);
    };
    const float* y2p = g_y2 + h * CODEBOOK + cbase;

    // issue stage 0 staging first (overlaps the A-frag build's loads)
    stage_issue(0, 0);

    // A fragments a[level][khalf], split on the fly from fp32 x (rt=1)
    f16x8 a[2][2];
#pragma unroll
    for (int kh = 0; kh < 2; kh++) {
        const float* xp = x + ((size_t)(qbase + col) * 256 + h * 64 + kh * 32 + quad * 8);
#pragma unroll
        for (int j = 0; j < 8; j++) {
            _Float16 h0, h1;
            split2(xp[j], h0, h1);
            a[0][kh][j] = h0;
            a[1][kh][j] = h1;
        }
    }

    float bv[4]; int bc[4];
#pragma unroll
    for (int r = 0; r < 4; r++) { bv[r] = -3.4e38f; bc[r] = 0; }

    __syncthreads();                               // stage 0 landed

    const int swbase = col & 7;                    // read-side swizzle key
    const f32x4 z4 = {0.f, 0.f, 0.f, 0.f};        // persistent zero C-operand

    for (int s = 0; s < NSTAGE; s++) {
        // issue next stage's DMA into the other buffer; it has the whole
        // inner loop to land; __syncthreads' vmcnt(0) drain completes it.
        if (s + 1 < NSTAGE) stage_issue(s + 1, (s + 1) & 1);

#pragma unroll
        for (int inner = 0; inner < 2; inner++) {
            const int rbase = (inner * 16 + col) * HD;     // row offset in plane
            f16x8 b[2][2];
#pragma unroll
            for (int lvl = 0; lvl < 2; lvl++)
#pragma unroll
                for (int kh = 0; kh < 2; kh++)
                    b[lvl][kh] = *reinterpret_cast<const f16x8*>(
                        &tile[s & 1][lvl][rbase + ((((kh << 2) | quad) ^ swbase) << 3)]);

            const int   cl  = inner * 16 + col;            // stage-local code
            const int   c   = s * SCODES + cl;             // partition-local code
            const float ycn = y2p[c];                      // -0.5*||e_c||^2 (L1-hot)

            __builtin_amdgcn_s_setprio(1);
            f32x4 aA = __builtin_amdgcn_mfma_f32_16x16x32_f16(a[0][0], b[0][0], z4, 0, 0, 0);
            f32x4 aB = __builtin_amdgcn_mfma_f32_16x16x32_f16(a[0][0], b[1][0], z4, 0, 0, 0);
            aB = __builtin_amdgcn_mfma_f32_16x16x32_f16(a[1][0], b[0][0], aB, 0, 0, 0);
            aA = __builtin_amdgcn_mfma_f32_16x16x32_f16(a[0][1], b[0][1], aA, 0, 0, 0);
            aB = __builtin_amdgcn_mfma_f32_16x16x32_f16(a[0][1], b[1][1], aB, 0, 0, 0);
            aB = __builtin_amdgcn_mfma_f32_16x16x32_f16(a[1][1], b[0][1], aB, 0, 0, 0);
            __builtin_amdgcn_s_setprio(0);
#pragma unroll
            for (int r = 0; r < 4; r++) {
                float sv = fmaf(aB[r], RINV, aA[r] + ycn);   // xy - 0.5||e||^2
                if (sv > bv[r]) { bv[r] = sv; bc[r] = c; }
            }
        }
        __syncthreads();
    }

    // reduce across 16 column slots; lexicographic (max val, min idx) =
    // np first-argmax tie-break; publish via packed device-scope atomicMax
#pragma unroll
    for (int r = 0; r < 4; r++) {
        float v = bv[r]; int c = bc[r];
#pragma unroll
        for (int off = 8; off >= 1; off >>= 1) {
            float ov = __shfl_xor(v, off, 16); int oc = __shfl_xor(c, off, 16);
            if (ov > v || (ov == v && oc < c)) { v = ov; c = oc; }
        }
        if (col == 0) {
            int q = h * BQ + qbase + quad * 4 + r;
            unsigned long long pk =
                ((unsigned long long)sortable(v) << 32) | (unsigned)(~(cbase + c));
            atomicMax(&g_best[q], pk);
        }
    }

    // ---------------- election: last block of the (h,qg) group finalizes ---
    // Plain __syncthreads: its vmcnt(0)+lgkmcnt(0) drain is load-bearing
    // (all atomicMaxes at the coherent point before t0's add). No threadfence.
    const int grp = (h << 7) | qg;
    __syncthreads();
    if (t == 0) s_old = atomicAdd(&g_cnt[grp], 1);
    __syncthreads();
    if (s_old != NPART - 1) return;  // not last -> done

    if (t == 0) atomicExch(&g_cnt[grp], 0);  // self-reset for next launch/replay

    // finalize 64 queries of (h,qg): coherent read via atomic RMW (add 0)
    int* sidx = reinterpret_cast<int*>(tile);    // tile dead; park 64 idx
    const int m0 = qg * QBLOCK;
    if (t < QBLOCK) {
        const int q = h * BQ + m0 + t;
        unsigned long long pk = atomicAdd(&g_best[q], 0ull);
        int mc = (int)(~(unsigned)pk) & (CODEBOOK - 1);
        out[QOFF + (size_t)(m0 + t) * 4 + h] = (float)mc;   // embed_ind[b][n][h]
        sidx[t] = mc;
    }
    __syncthreads();

    // gather: wave owns 16 rows; 16 lanes per row x 4 rows per iter -> fully
    // coalesced 256B reads per codebook row and 256B stores per output row.
    const int rr = lane >> 4;                    // row-in-quad 0..3
    const int fo = (lane & 15) * 4;              // float offset within head seg
#pragma unroll
    for (int i = 0; i < 4; i++) {
        const int r   = wave * 16 + i * 4 + rr;
        const int idx = sidx[r];
        const float4 v = *reinterpret_cast<const float4*>(
            embed + ((size_t)h * CODEBOOK + idx) * HD + fo);
        *reinterpret_cast<float4*>(out + (size_t)(m0 + r) * 256 + h * 64 + fo) = v;
    }
}

extern "C" void kernel_launch(void* const* d_in, const int* in_sizes, int n_in,
                              void* d_out, int out_size, void* d_ws, size_t ws_size,
                              hipStream_t stream) {
    const float* x     = (const float*)d_in[0];
    const float* embed = (const float*)d_in[1];
    float*       out   = (float*)d_out;

    prep_kernel<<<1024, 256, 0, stream>>>(embed);
    dist_kernel<<<4096, 256, 0, stream>>>(x, embed, out);
}

// Round 14
// 176.336 us; speedup vs baseline: 1.1485x; 1.1485x over previous
//
#include <hip/hip_runtime.h>

// VectorQuantize: B=4, N=2048, DIM=256, HEADS=4, CODEBOOK=8192, HD=64
// Established: inputs fp32, output fp32 (quantize ++ indices-as-floats).
// R10: fp16 2-level split, 3 MFMA terms. R11: setprio+z-init: dist 128.
// R12: threadfence fusion DISASTER. R13: fence-free atomic fusion 137/176.
// R15: counted-wait barriers NEUTRAL. R16: prep planes + gl_lds: 131.5/176.0
//   (BEST; reproduced R19 176.9, R22 177.2). R17: private tiles REGRESSED.
// R18: coop launch = harness crash. R20: 5 w/SIMD = invalid slot (spill).
// R21: 32x32 shape CLOSED (acc state spills + inherent 4-way LDS conflict).
// R23: VALID 8-wave probe: occupancy 19->69%, dist WORSE (145), MfmaUtil
//   pinned at 32 => occupancy theory decisively falsified. Seven structural
//   variants all land dist 128-145 with MfmaUtil 31-35: the wall is
//   intra-wave dependent-chain latency, not recoverable by TLP/schedule.
// R24 (this round): restore the verified optimum (R16 body verbatim).
//   All levers closed by controlled measurements. Expected: dist ~130,
//   total ~176-177. If reproduced (4th time), this is the declared floor.

#define HEADS    4
#define CODEBOOK 8192
#define HD       64
#define BQ       8192                  // queries per head = B*N
#define QOFF     (4 * 2048 * 256)      // quantize FLOAT elements in d_out
#define NPART    8
#define CPART    (CODEBOOK / NPART)    // 1024 codes per partition
#define SCODES   64                    // codes per stage
#define NSTAGE   (CPART / SCODES)      // 16 stages
#define RSCALE   4096.0f               // residual scale (2^12)
#define RINV     (1.0f / 4096.0f)

typedef _Float16 f16x8 __attribute__((ext_vector_type(8)));
typedef float    f32x4 __attribute__((ext_vector_type(4)));

__device__ _Float16 g_e0[HEADS * CODEBOOK * HD];  // 4 MB: fp16 level-0 plane
__device__ _Float16 g_e1[HEADS * CODEBOOK * HD];  // 4 MB: fp16 level-1 plane
__device__ float    g_y2[HEADS * CODEBOOK];       // -0.5*||e||^2
__device__ unsigned long long g_best[HEADS * BQ]; // packed (sortable score, ~idx)
__device__ int                g_cnt[HEADS * 32];  // per-(h,qg) arrival counter

// split fp32 -> 2 fp16 levels: f ~= (float)h0 + (float)h1 / 4096, |err|<=2^-24|f|
__device__ inline void split2(float f, _Float16& h0, _Float16& h1) {
    h0 = (_Float16)f;
    float r = f - (float)h0;
    h1 = (_Float16)(r * RSCALE);
}

// order-preserving float->uint32 (finite values; scores are finite)
__device__ inline unsigned sortable(float v) {
    unsigned s = __float_as_uint(v);
    return s ^ ((s & 0x80000000u) ? 0xFFFFFFFFu : 0x80000000u);
}

__device__ inline void gl_lds16(const void* g, void* l) {
    __builtin_amdgcn_global_load_lds(
        (const __attribute__((address_space(1))) void*)g,
        (__attribute__((address_space(3))) void*)l, 16, 0, 0);
}

// ---------------- kernel 0: pre-split embed into global planes ------------
// 1024 blocks x 256 thr; 8 threads per code row (granule t&7), 32 rows/block.
// Coalesced: wave reads 2KB contiguous, writes 1KB contiguous per plane.
__global__ __launch_bounds__(256) void prep_kernel(const float* __restrict__ embed) {
    const int t   = threadIdx.x;
    const int row = blockIdx.x * 32 + (t >> 3);    // h*CODEBOOK + c
    const int g   = t & 7;
    const float* p = embed + (size_t)row * HD + g * 8;
    float f[8];
    *reinterpret_cast<float4*>(&f[0]) = *reinterpret_cast<const float4*>(p);
    *reinterpret_cast<float4*>(&f[4]) = *reinterpret_cast<const float4*>(p + 4);
    f16x8 v0, v1;
    float ss = 0.f;
#pragma unroll
    for (int j = 0; j < 8; j++) {
        _Float16 h0, h1;
        split2(f[j], h0, h1);
        v0[j] = h0; v1[j] = h1;
        ss = fmaf(f[j], f[j], ss);
    }
    *reinterpret_cast<f16x8*>(&g_e0[(size_t)row * HD + g * 8]) = v0;
    *reinterpret_cast<f16x8*>(&g_e1[(size_t)row * HD + g * 8]) = v1;
#pragma unroll
    for (int off = 4; off >= 1; off >>= 1)
        ss += __shfl_xor(ss, off, 8);
    if (g == 0) g_y2[row] = -0.5f * ss;
}

// ---------------- kernel 1: fused scores + argmax + election merge --------
// grid = 1024 = head(4) x qgroup(32) x part(8); block = 256 (4 waves).
// Each wave owns 64 queries (4 pinned A row-tiles); block scans one 1024-code
// partition in 16 stages of 64 codes. Staging = 16 global_load_lds (16B) per
// stage per block (4/wave: wave w covers plane w&1, rows (w>>1)*32..+31),
// source pre-swizzled so LDS layout == verified conflict-free tile:
// LDS slot g of row rr holds global granule g^(rr&7).
// MFMA 16x16x32_f16 layouts (HW-verified family):
//   A: lane -> A[m=lane&15][k=quad*8+j];  B: lane -> B[k=quad*8+j][n=lane&15]
//   C: lane -> col=lane&15, row=quad*4+reg
__global__ __launch_bounds__(256, 2) void dist_kernel(const float* __restrict__ x,
                                                      const float* __restrict__ embed,
                                                      float* __restrict__ out) {
    __shared__ __align__(16) _Float16 tile[2][2][SCODES * HD];   // 32768 B
    __shared__ int s_old;

    const int bid  = blockIdx.x;
    const int part = bid & 7;
    const int qg   = (bid >> 3) & 31;
    const int h    = bid >> 8;
    const int t    = threadIdx.x;
    const int wave = t >> 6;
    const int lane = t & 63;
    const int col  = lane & 15;
    const int quad = lane >> 4;

    const int qbase = qg * 256 + wave * 64;       // this wave's 64 queries
    const int cbase = part * CPART;

    // staging geometry: wave covers plane (wave&1), rows (wave>>1)*32..+31.
    // lane l: row-in-chunk l>>3, LDS slot l&7 (HW lane-linear), source
    // granule (l&7)^(l>>3)  [row&7 == l>>3 since all bases are %8==0].
    const int p  = wave & 1;
    const int hh = wave >> 1;
    const _Float16* eb   = p ? g_e1 : g_e0;
    const _Float16* gsrc = eb
        + ((size_t)(h * CODEBOOK + cbase + hh * 32 + (lane >> 3))) * HD
        + ((lane & 7) ^ (lane >> 3)) * 8;
    auto stage_issue = [&](int st, int buf) {
        const _Float16* src = gsrc + (size_t)st * (SCODES * HD);
#pragma unroll
        for (int i = 0; i < 4; i++)
            gl_lds16(src + i * 8 * HD, &tile[buf][p][(hh * 32 + i * 8) * HD]);
    };
    const float* y2p = g_y2 + h * CODEBOOK + cbase;

    // issue stage 0 staging first (overlaps the A-frag build's loads)
    stage_issue(0, 0);

    // A fragments a[rowtile][level][khalf], split on the fly from fp32 x
    f16x8 a[4][2][2];
#pragma unroll
    for (int rt = 0; rt < 4; rt++) {
#pragma unroll
        for (int kh = 0; kh < 2; kh++) {
            const float* xp = x + ((size_t)(qbase + rt * 16 + col) * 256 + h * 64 + kh * 32 + quad * 8);
#pragma unroll
            for (int j = 0; j < 8; j++) {
                _Float16 h0, h1;
                split2(xp[j], h0, h1);
                a[rt][0][kh][j] = h0;
                a[rt][1][kh][j] = h1;
            }
        }
    }

    float bv[4][4]; int bc[4][4];
#pragma unroll
    for (int rt = 0; rt < 4; rt++)
#pragma unroll
        for (int r = 0; r < 4; r++) { bv[rt][r] = -3.4e38f; bc[rt][r] = 0; }

    __syncthreads();                               // stage 0 landed

    const int swbase = col & 7;                    // read-side swizzle key
    const f32x4 z4 = {0.f, 0.f, 0.f, 0.f};        // persistent zero C-operand

    for (int s = 0; s < NSTAGE; s++) {
        // issue next stage's DMA into the other buffer; it has the whole
        // inner loop to land; __syncthreads' vmcnt(0) drain completes it.
        if (s + 1 < NSTAGE) stage_issue(s + 1, (s + 1) & 1);

#pragma unroll
        for (int inner = 0; inner < 4; inner++) {
            const int rbase = (inner * 16 + col) * HD;     // row offset in plane
            f16x8 b[2][2];
#pragma unroll
            for (int lvl = 0; lvl < 2; lvl++)
#pragma unroll
                for (int kh = 0; kh < 2; kh++)
                    b[lvl][kh] = *reinterpret_cast<const f16x8*>(
                        &tile[s & 1][lvl][rbase + ((((kh << 2) | quad) ^ swbase) << 3)]);

            const int   cl  = inner * 16 + col;            // stage-local code
            const int   c   = s * SCODES + cl;             // partition-local code
            const float ycn = y2p[c];                      // -0.5*||e_c||^2 (L1-hot)
#pragma unroll
            for (int rt = 0; rt < 4; rt++) {
                __builtin_amdgcn_s_setprio(1);
                f32x4 aA = __builtin_amdgcn_mfma_f32_16x16x32_f16(a[rt][0][0], b[0][0], z4, 0, 0, 0);
                f32x4 aB = __builtin_amdgcn_mfma_f32_16x16x32_f16(a[rt][0][0], b[1][0], z4, 0, 0, 0);
                aB = __builtin_amdgcn_mfma_f32_16x16x32_f16(a[rt][1][0], b[0][0], aB, 0, 0, 0);
                aA = __builtin_amdgcn_mfma_f32_16x16x32_f16(a[rt][0][1], b[0][1], aA, 0, 0, 0);
                aB = __builtin_amdgcn_mfma_f32_16x16x32_f16(a[rt][0][1], b[1][1], aB, 0, 0, 0);
                aB = __builtin_amdgcn_mfma_f32_16x16x32_f16(a[rt][1][1], b[0][1], aB, 0, 0, 0);
                __builtin_amdgcn_s_setprio(0);
#pragma unroll
                for (int r = 0; r < 4; r++) {
                    float sv = fmaf(aB[r], RINV, aA[r] + ycn); // xy - 0.5||e||^2
                    if (sv > bv[rt][r]) { bv[rt][r] = sv; bc[rt][r] = c; }
                }
            }
        }
        __syncthreads();
    }

    // reduce across 16 column slots; lexicographic (max val, min idx) =
    // np first-argmax tie-break; publish via packed device-scope atomicMax
#pragma unroll
    for (int rt = 0; rt < 4; rt++) {
#pragma unroll
        for (int r = 0; r < 4; r++) {
            float v = bv[rt][r]; int c = bc[rt][r];
#pragma unroll
            for (int off = 8; off >= 1; off >>= 1) {
                float ov = __shfl_xor(v, off, 16); int oc = __shfl_xor(c, off, 16);
                if (ov > v || (ov == v && oc < c)) { v = ov; c = oc; }
            }
            if (col == 0) {
                int q = h * BQ + qbase + rt * 16 + quad * 4 + r;
                unsigned long long pk =
                    ((unsigned long long)sortable(v) << 32) | (unsigned)(~(cbase + c));
                atomicMax(&g_best[q], pk);
            }
        }
    }

    // ---------------- election: last block of the (h,qg) group finalizes ---
    // Plain __syncthreads: its vmcnt(0)+lgkmcnt(0) drain is load-bearing
    // (all atomicMaxes at the coherent point before t0's add). R12 lesson:
    // no __threadfence.
    const int grp = (h << 5) | qg;
    __syncthreads();
    if (t == 0) s_old = atomicAdd(&g_cnt[grp], 1);
    __syncthreads();
    if (s_old != NPART - 1) return;  // not last -> done

    if (t == 0) atomicExch(&g_cnt[grp], 0);  // self-reset for next launch/replay

    // finalize 256 queries of (h,qg): coherent read via atomic RMW (add 0)
    int* sidx = reinterpret_cast<int*>(tile);    // tile dead; park 256 idx
    const int m0 = qg * 256;
    {
        const int q = h * BQ + m0 + t;
        unsigned long long pk = atomicAdd(&g_best[q], 0ull);
        int mc = (int)(~(unsigned)pk) & (CODEBOOK - 1);
        out[QOFF + (size_t)(m0 + t) * 4 + h] = (float)mc;   // embed_ind[b][n][h]
        sidx[t] = mc;
    }
    __syncthreads();

    // gather: wave owns 64 rows; 16 lanes per row x 4 rows per iter -> fully
    // coalesced 256B reads per codebook row and 256B stores per output row.
    const int rr = lane >> 4;                    // row-in-quad 0..3
    const int fo = (lane & 15) * 4;              // float offset within head seg
#pragma unroll
    for (int i = 0; i < 16; i++) {
        const int r   = wave * 64 + i * 4 + rr;
        const int idx = sidx[r];
        const float4 v = *reinterpret_cast<const float4*>(
            embed + ((size_t)h * CODEBOOK + idx) * HD + fo);
        *reinterpret_cast<float4*>(out + (size_t)(m0 + r) * 256 + h * 64 + fo) = v;
    }
}

extern "C" void kernel_launch(void* const* d_in, const int* in_sizes, int n_in,
                              void* d_out, int out_size, void* d_ws, size_t ws_size,
                              hipStream_t stream) {
    const float* x     = (const float*)d_in[0];
    const float* embed = (const float*)d_in[1];
    float*       out   = (float*)d_out;

    prep_kernel<<<1024, 256, 0, stream>>>(embed);
    dist_kernel<<<1024, 256, 0, stream>>>(x, embed, out);
}